// Round 8
// baseline (121.157 us; speedup 1.0000x reference)
//
#include <hip/hip_runtime.h>
#include <hip/hip_bf16.h>

typedef __attribute__((ext_vector_type(8))) __bf16 bf16x8;
typedef __attribute__((ext_vector_type(4))) __bf16 bf16x4;
typedef __attribute__((ext_vector_type(4))) float f32x4;

#define DIM 1024
#define SLEN 2048
#define NH 16
#define HD 64

__device__ __forceinline__ f32x4 MFMA(bf16x8 a, bf16x8 b, f32x4 c) {
    return __builtin_amdgcn_mfma_f32_16x16x32_bf16(a, b, c, 0, 0, 0);
}

// ---------------- f32 -> bf16 convert (n % 8 == 0) ----------------
__global__ __launch_bounds__(256) void cvt_bf16(const float* __restrict__ in,
                                                __bf16* __restrict__ out, int n) {
    int i = (blockIdx.x * blockDim.x + threadIdx.x) * 8;
    if (i >= n) return;
    f32x4 a = *reinterpret_cast<const f32x4*>(in + i);
    f32x4 b = *reinterpret_cast<const f32x4*>(in + i + 4);
    bf16x8 o;
#pragma unroll
    for (int j = 0; j < 4; ++j) { o[j] = (__bf16)a[j]; o[j + 4] = (__bf16)b[j]; }
    *reinterpret_cast<bf16x8*>(out + i) = o;
}

// 4 weight matrices in one launch (blockIdx.y selects)
__global__ __launch_bounds__(256) void cvt_w4(const float* __restrict__ w0,
                                              const float* __restrict__ w1,
                                              const float* __restrict__ w2,
                                              const float* __restrict__ w3,
                                              __bf16* __restrict__ o0,
                                              __bf16* __restrict__ o1,
                                              __bf16* __restrict__ o2,
                                              __bf16* __restrict__ o3) {
    int s = blockIdx.y;
    const float* in = s == 0 ? w0 : s == 1 ? w1 : s == 2 ? w2 : w3;
    __bf16* out = s == 0 ? o0 : s == 1 ? o1 : s == 2 ? o2 : o3;
    int i = (blockIdx.x * blockDim.x + threadIdx.x) * 8;
    f32x4 a = *reinterpret_cast<const f32x4*>(in + i);
    f32x4 b = *reinterpret_cast<const f32x4*>(in + i + 4);
    bf16x8 o;
#pragma unroll
    for (int j = 0; j < 4; ++j) { o[j] = (__bf16)a[j]; o[j + 4] = (__bf16)b[j]; }
    *reinterpret_cast<bf16x8*>(out + i) = o;
}

// ---------------- RoPE on q and k in one launch --------------------------------
__global__ __launch_bounds__(256) void rope2(__bf16* __restrict__ q,
                                             __bf16* __restrict__ k) {
    __bf16* t = blockIdx.y == 0 ? q : k;
    // fold softmax scale (1/8)*log2(e) into q so attention can use exp2
    const float scale = blockIdx.y == 0 ? 0.18033688011112042f : 1.0f;
    int idx = blockIdx.x * blockDim.x + threadIdx.x;
    int row = idx >> 9;
    int p = idx & 511;
    int head = p >> 5;
    int j = p & 31;
    int s = row & (SLEN - 1);
    float inv = expf(-0.28782313662425574f * (float)j);
    float angle = (float)s * inv;
    float sn, cs;
    sincosf(angle, &sn, &cs);
    size_t base = (size_t)row * DIM + head * HD + 2 * j;
    float e = (float)t[base], o = (float)t[base + 1];
    t[base] = (__bf16)((e * cs - o * sn) * scale);
    t[base + 1] = (__bf16)((e * sn + o * cs) * scale);
}

// ---------------- fused QKV GEMM: 128x128 tile, BK=64, swizzled LDS -----------
// Q,K row-major [token][dim]; V TRANSPOSED: Vt[(b*16+h)*64+d][s]
__global__ __launch_bounds__(256) void gemm_qkv(const __bf16* __restrict__ X,
                                                const __bf16* __restrict__ Wq,
                                                const __bf16* __restrict__ Wk,
                                                const __bf16* __restrict__ Wv,
                                                __bf16* __restrict__ Qo,
                                                __bf16* __restrict__ Ko,
                                                __bf16* __restrict__ Vt) {
    __shared__ alignas(16) __bf16 Alds[128 * 64];
    __shared__ alignas(16) __bf16 Blds[128 * 64];
    const int tid = threadIdx.x;
    const int lane = tid & 63;
    const int w = tid >> 6;
    const int wr = w >> 1, wc = w & 1;
    const int l15 = lane & 15, lhi = lane >> 4;
    const int l7 = l15 & 7;
    const int m0 = blockIdx.y * 128;
    const int n0g = blockIdx.x * 128;
    const int seg = n0g >> 10;
    const int n0 = n0g & 1023;
    const __bf16* __restrict__ B = seg == 0 ? Wq : seg == 1 ? Wk : Wv;
    const int K = 1024, N = 1024;

    const int lrow = lane >> 3;                 // 0..7
    const int scol = ((lane & 7) ^ lrow) * 8;   // source-side XOR swizzle

    f32x4 acc[4][4] = {};

    for (int kt = 0; kt < K; kt += 64) {
#pragma unroll
        for (int c = 0; c < 4; ++c) {
            int r0 = c * 32 + w * 8;
            const __bf16* sa = &X[(size_t)(m0 + r0 + lrow) * K + kt + scol];
            const __bf16* sb = &B[(size_t)(n0 + r0 + lrow) * K + kt + scol];
            __builtin_amdgcn_global_load_lds((const __attribute__((address_space(1))) void*)sa,
                                             (__attribute__((address_space(3))) void*)&Alds[r0 * 64],
                                             16, 0, 0);
            __builtin_amdgcn_global_load_lds((const __attribute__((address_space(1))) void*)sb,
                                             (__attribute__((address_space(3))) void*)&Blds[r0 * 64],
                                             16, 0, 0);
        }
        __syncthreads();
#pragma unroll
        for (int kk = 0; kk < 2; ++kk) {
            bf16x8 af[4], bfr[4];
#pragma unroll
            for (int i = 0; i < 4; ++i) {
                af[i] = *(const bf16x8*)&Alds[(wr * 64 + i * 16 + l15) * 64 + 8 * ((kk * 4 + lhi) ^ l7)];
                bfr[i] = *(const bf16x8*)&Blds[(wc * 64 + i * 16 + l15) * 64 + 8 * ((kk * 4 + lhi) ^ l7)];
            }
            __builtin_amdgcn_s_setprio(1);
#pragma unroll
            for (int i = 0; i < 4; ++i)
#pragma unroll
                for (int j = 0; j < 4; ++j)
                    acc[i][j] = MFMA(af[i], bfr[j], acc[i][j]);
            __builtin_amdgcn_s_setprio(0);
        }
        __syncthreads();
    }
    if (seg < 2) {
        __bf16* __restrict__ O = seg == 0 ? Qo : Ko;
#pragma unroll
        for (int i = 0; i < 4; ++i)
#pragma unroll
            for (int j = 0; j < 4; ++j)
#pragma unroll
                for (int r = 0; r < 4; ++r) {
                    int row = m0 + wr * 64 + i * 16 + lhi * 4 + r;
                    int col = n0 + wc * 64 + j * 16 + l15;
                    O[(size_t)row * N + col] = (__bf16)acc[i][j][r];
                }
    } else {
        // V: write transposed Vt[(b*16+h)*64 + d][s], packed over 4 consecutive s
#pragma unroll
        for (int i = 0; i < 4; ++i)
#pragma unroll
            for (int j = 0; j < 4; ++j) {
                int row = m0 + wr * 64 + i * 16 + lhi * 4;  // token base, mult of 4
                int col = n0 + wc * 64 + j * 16 + l15;      // dim
                int bb = row >> 11, s = row & 2047;
                int hh = col >> 6, d = col & 63;
                bf16x4 pk;
#pragma unroll
                for (int r = 0; r < 4; ++r) pk[r] = (__bf16)acc[i][j][r];
                *(bf16x4*)&Vt[((size_t)(bb * 16 + hh) * 64 + d) * SLEN + s] = pk;
            }
    }
}

// ---------------- O-projection GEMM: 64x128 tile, f32 out, 512 blocks ---------
__global__ __launch_bounds__(256) void gemm_o(const __bf16* __restrict__ A,
                                              const __bf16* __restrict__ B,
                                              float* __restrict__ C) {
    __shared__ alignas(16) __bf16 Alds[64 * 64];
    __shared__ alignas(16) __bf16 Blds[128 * 64];
    const int tid = threadIdx.x;
    const int lane = tid & 63;
    const int w = tid >> 6;
    const int wr = w >> 1, wc = w & 1;
    const int l15 = lane & 15, lhi = lane >> 4;
    const int l7 = l15 & 7;
    const int m0 = blockIdx.y * 64;
    const int n0 = blockIdx.x * 128;
    const int K = 1024, N = 1024;

    const int lrow = lane >> 3;
    const int scol = ((lane & 7) ^ lrow) * 8;

    f32x4 acc[2][4] = {};

    for (int kt = 0; kt < K; kt += 64) {
#pragma unroll
        for (int c = 0; c < 2; ++c) {
            int r0 = c * 32 + w * 8;
            const __bf16* sa = &A[(size_t)(m0 + r0 + lrow) * K + kt + scol];
            __builtin_amdgcn_global_load_lds((const __attribute__((address_space(1))) void*)sa,
                                             (__attribute__((address_space(3))) void*)&Alds[r0 * 64],
                                             16, 0, 0);
        }
#pragma unroll
        for (int c = 0; c < 4; ++c) {
            int r0 = c * 32 + w * 8;
            const __bf16* sb = &B[(size_t)(n0 + r0 + lrow) * K + kt + scol];
            __builtin_amdgcn_global_load_lds((const __attribute__((address_space(1))) void*)sb,
                                             (__attribute__((address_space(3))) void*)&Blds[r0 * 64],
                                             16, 0, 0);
        }
        __syncthreads();
#pragma unroll
        for (int kk = 0; kk < 2; ++kk) {
            bf16x8 af[2], bfr[4];
#pragma unroll
            for (int i = 0; i < 2; ++i)
                af[i] = *(const bf16x8*)&Alds[(wr * 32 + i * 16 + l15) * 64 + 8 * ((kk * 4 + lhi) ^ l7)];
#pragma unroll
            for (int j = 0; j < 4; ++j)
                bfr[j] = *(const bf16x8*)&Blds[(wc * 64 + j * 16 + l15) * 64 + 8 * ((kk * 4 + lhi) ^ l7)];
            __builtin_amdgcn_s_setprio(1);
#pragma unroll
            for (int i = 0; i < 2; ++i)
#pragma unroll
                for (int j = 0; j < 4; ++j)
                    acc[i][j] = MFMA(af[i], bfr[j], acc[i][j]);
            __builtin_amdgcn_s_setprio(0);
        }
        __syncthreads();
    }
#pragma unroll
    for (int i = 0; i < 2; ++i)
#pragma unroll
        for (int j = 0; j < 4; ++j)
#pragma unroll
            for (int r = 0; r < 4; ++r) {
                int row = m0 + wr * 32 + i * 16 + lhi * 4 + r;
                int col = n0 + wc * 64 + j * 16 + l15;
                C[(size_t)row * N + col] = acc[i][j][r];
            }
}

// ---------------- causal flash attention, O^T form, 2 q-frags per wave --------
// 1024 blocks x 128 threads (2 waves): 64-q tile per block, 32 q per wave
// (fragments A: q=w*32+l15, B: +16). Halves LDS bytes per MFMA (K/V fragment
// reads amortized over 2 fragments). Static softmax max (exp2(S-16)); row-sum
// via ones-MFMA. LDS exactly 40960 B -> 4 blocks/CU.
__global__ __launch_bounds__(128, 2) void attn_kernel(const __bf16* __restrict__ Q,
                                                      const __bf16* __restrict__ K,
                                                      const __bf16* __restrict__ Vt,
                                                      __bf16* __restrict__ Y) {
    __shared__ __bf16 Klds[2][64 * 64];   // [key][d-blocks swizzled]
    __shared__ __bf16 Vlds[2][64 * 64];   // [d][key-blocks swizzled]
    __shared__ __bf16 Plds[2][32][64];    // per-wave P[q 0..31][key], chunk-XOR

    const int tid = threadIdx.x;
    const int lane = tid & 63;
    const int w = tid >> 6;               // 0..1
    const int l15 = lane & 15, lhi = lane >> 4;
    const int l7 = l15 & 7;
    const int l14 = l15 & 14;

    // id&7 = XCD; within XCD: qt descending (LPT), interleaved over 4 bh streams
    const int id = blockIdx.x;            // 0..1023
    const int x = id & 7, j = id >> 3;    // j 0..127
    const int qt = 31 - (j >> 2);         // 31..0
    const int bh = 4 * x + (j & 3);       // 4 streams per XCD (2MB L2 working set)
    const int b = bh >> 4, h = bh & 15;

    const int srow = lane >> 3;
    const int scs = (lane & 7) ^ srow;

    // moving staging pointers; 2 waves x 4 iters x 8 rows cover 64 rows
    const __bf16* skP = K + (size_t)b * SLEN * DIM + h * HD + (size_t)(8 * w + srow) * DIM + scs * 8;
    const __bf16* svP = Vt + (size_t)bh * 64 * SLEN + (size_t)(8 * w + srow) * SLEN + scs * 8;
    const int dBase = (8 * w + srow) * 64;

    // precomputed LDS read offsets (compile-time-indexed after unroll)
    int koffs[4][2], voffs[2][4], pw[4];
#pragma unroll
    for (int nb = 0; nb < 4; ++nb) {
        koffs[nb][0] = (nb * 16 + l15) * 64 + 8 * (lhi ^ l7);
        koffs[nb][1] = (nb * 16 + l15) * 64 + 8 * ((4 + lhi) ^ l7);
        pw[nb] = ((nb * 4 + lhi) ^ l14) * 4;
    }
#pragma unroll
    for (int kk = 0; kk < 2; ++kk)
#pragma unroll
        for (int nd = 0; nd < 4; ++nd)
            voffs[kk][nd] = (nd * 16 + l15) * 64 + 8 * ((kk * 4 + lhi) ^ l7);
    const int pr0 = ((lhi * 2) ^ l14) * 4;
    const int pr1 = ((8 + lhi * 2) ^ l14) * 4;
    __bf16* PmeA = &Plds[w][l15][0];
    __bf16* PmeB = &Plds[w][16 + l15][0];

    const int qlocA = w * 32 + l15;       // local q row within the 64-q tile
    const int qlocB = qlocA + 16;
    const int qgA = qt * 64 + qlocA;
    const size_t qbaseA = (size_t)(b * SLEN + qgA) * DIM + h * HD;
    const bf16x8 qfA0 = *(const bf16x8*)&Q[qbaseA + lhi * 8];
    const bf16x8 qfA1 = *(const bf16x8*)&Q[qbaseA + 32 + lhi * 8];
    const bf16x8 qfB0 = *(const bf16x8*)&Q[qbaseA + 16 * DIM + lhi * 8];
    const bf16x8 qfB1 = *(const bf16x8*)&Q[qbaseA + 16 * DIM + 32 + lhi * 8];

    bf16x8 ones;
#pragma unroll
    for (int t = 0; t < 8; ++t) ones[t] = (__bf16)1.0f;

    f32x4 accA[4] = {}, accB[4] = {};  // acc[nd][r]: d = nd*16 + lhi*4 + r
    f32x4 accLA = {}, accLB = {};      // P row-sums via ones-MFMA

    auto stage = [&](int buf) {
#pragma unroll
        for (int i = 0; i < 4; ++i) {
            __builtin_amdgcn_global_load_lds(
                (const __attribute__((address_space(1))) void*)(skP + (size_t)i * 16 * DIM),
                (__attribute__((address_space(3))) void*)&Klds[buf][dBase + i * 16 * 64], 16, 0, 0);
            __builtin_amdgcn_global_load_lds(
                (const __attribute__((address_space(1))) void*)(svP + (size_t)i * 16 * SLEN),
                (__attribute__((address_space(3))) void*)&Vlds[buf][dBase + i * 16 * 64], 16, 0, 0);
        }
        skP += 64 * DIM;   // next kv tile: +64 key rows
        svP += 64;         // next kv tile: +64 key columns
    };

    const int nkt = qt + 1;  // kv tiles 0..qt
    stage(0);
    for (int kt = 0; kt < nkt; ++kt) {
        const int cur = kt & 1;
        __syncthreads();  // drains vmcnt: buf[cur] staged; buf[cur^1] free
        if (kt + 1 < nkt) stage(cur ^ 1);
        const __bf16* Kc = Klds[cur];
        const __bf16* Vc = Vlds[cur];

        // ---- S^T = K Q^T for both q-fragments (K-frags shared) ----
        f32x4 sA[4], sB[4];
        __builtin_amdgcn_s_setprio(1);
#pragma unroll
        for (int nb = 0; nb < 4; ++nb) {
            bf16x8 k0 = *(const bf16x8*)&Kc[koffs[nb][0]];
            bf16x8 k1 = *(const bf16x8*)&Kc[koffs[nb][1]];
            f32x4 a = {};
            a = MFMA(k0, qfA0, a);
            a = MFMA(k1, qfA1, a);
            sA[nb] = a;
            f32x4 c = {};
            c = MFMA(k0, qfB0, c);
            c = MFMA(k1, qfB1, c);
            sB[nb] = c;
        }
        __builtin_amdgcn_s_setprio(0);
        if (kt == qt) {  // only the diagonal tile is partially masked
#pragma unroll
            for (int nb = 0; nb < 4; ++nb)
#pragma unroll
                for (int r = 0; r < 4; ++r) {
                    const int key = nb * 16 + lhi * 4 + r;
                    if (key > qlocA) sA[nb][r] = -1e30f;
                    if (key > qlocB) sB[nb][r] = -1e30f;
                }
        }
        // ---- P = exp2(S - 16), packed b64 to LDS (both fragments) ----
#pragma unroll
        for (int nb = 0; nb < 4; ++nb) {
            bf16x4 pa, pb;
#pragma unroll
            for (int r = 0; r < 4; ++r) {
                pa[r] = (__bf16)exp2f(sA[nb][r] - 16.0f);
                pb[r] = (__bf16)exp2f(sB[nb][r] - 16.0f);
            }
            *(bf16x4*)&PmeA[pw[nb]] = pa;
            *(bf16x4*)&PmeB[pw[nb]] = pb;
        }

        // ---- O^T += V^T P^T (V-frags shared); row-sums via ones-MFMA ----
        __builtin_amdgcn_s_setprio(1);
        const bf16x8 pfA0 = *(const bf16x8*)&PmeA[pr0];
        const bf16x8 pfA1 = *(const bf16x8*)&PmeA[pr1];
        const bf16x8 pfB0 = *(const bf16x8*)&PmeB[pr0];
        const bf16x8 pfB1 = *(const bf16x8*)&PmeB[pr1];
        accLA = MFMA(ones, pfA0, accLA);
        accLA = MFMA(ones, pfA1, accLA);
        accLB = MFMA(ones, pfB0, accLB);
        accLB = MFMA(ones, pfB1, accLB);
#pragma unroll
        for (int nd = 0; nd < 4; ++nd) {
            bf16x8 v0 = *(const bf16x8*)&Vc[voffs[0][nd]];
            bf16x8 v1 = *(const bf16x8*)&Vc[voffs[1][nd]];
            accA[nd] = MFMA(v0, pfA0, accA[nd]);
            accA[nd] = MFMA(v1, pfA1, accA[nd]);
            accB[nd] = MFMA(v0, pfB0, accB[nd]);
            accB[nd] = MFMA(v1, pfB1, accB[nd]);
        }
        __builtin_amdgcn_s_setprio(0);
    }
    // ---- epilogue: lane-local 1/lsum, packed bf16x4 stores, both frags ----
    const float invA = 1.0f / accLA[0];
    const float invB = 1.0f / accLB[0];
    const size_t obase = (size_t)(b * SLEN + qgA) * DIM + h * HD;
#pragma unroll
    for (int nd = 0; nd < 4; ++nd) {
        bf16x4 oA, oB;
#pragma unroll
        for (int r = 0; r < 4; ++r) {
            oA[r] = (__bf16)(accA[nd][r] * invA);
            oB[r] = (__bf16)(accB[nd][r] * invB);
        }
        *(bf16x4*)&Y[obase + nd * 16 + lhi * 4] = oA;
        *(bf16x4*)&Y[obase + 16 * DIM + nd * 16 + lhi * 4] = oB;
    }
}

// ---------------- launcher ----------------
extern "C" void kernel_launch(void* const* d_in, const int* in_sizes, int n_in,
                              void* d_out, int out_size, void* d_ws, size_t ws_size,
                              hipStream_t stream) {
    const float* x = (const float*)d_in[0];
    const float* Wq = (const float*)d_in[1];
    const float* Wk = (const float*)d_in[2];
    const float* Wv = (const float*)d_in[3];
    const float* Wo = (const float*)d_in[4];
    float* out = (float*)d_out;

    const size_t XN = (size_t)4096 * 1024;
    const size_t WN = (size_t)1024 * 1024;

    __bf16* xb = (__bf16*)d_ws;
    __bf16* qb = xb + XN;
    __bf16* kb = qb + XN;
    __bf16* vtb = kb + XN;   // transposed V: [(b*16+h)*64 + d][SLEN]
    __bf16* wqb = vtb + XN;
    __bf16* wkb = wqb + WN;
    __bf16* wvb = wkb + WN;
    __bf16* wob = wvb + WN;
    __bf16* yb = xb;  // alias: attn writes y after x's last read (QKV GEMM)

    cvt_bf16<<<XN / 8 / 256, 256, 0, stream>>>(x, xb, (int)XN);
    dim3 gw(WN / 8 / 256, 4);
    cvt_w4<<<gw, 256, 0, stream>>>(Wq, Wk, Wv, Wo, wqb, wkb, wvb, wob);

    dim3 gq(24, 32);  // 3072/128 x 4096/128
    gemm_qkv<<<gq, 256, 0, stream>>>(xb, wqb, wkb, wvb, qb, kb, vtb);

    int pairs = 4096 * (DIM / 2);
    dim3 gr(pairs / 256, 2);
    rope2<<<gr, 256, 0, stream>>>(qb, kb);

    attn_kernel<<<1024, 128, 0, stream>>>(qb, kb, vtb, yb);

    dim3 go(8, 64);  // 1024/128 x 4096/64
    gemm_o<<<go, 256, 0, stream>>>(yb, wob, out);
}

// Round 9
// 111.120 us; speedup vs baseline: 1.0903x; 1.0903x over previous
//
#include <hip/hip_runtime.h>
#include <hip/hip_bf16.h>

typedef __attribute__((ext_vector_type(8))) __bf16 bf16x8;
typedef __attribute__((ext_vector_type(4))) __bf16 bf16x4;
typedef __attribute__((ext_vector_type(4))) float f32x4;
typedef __attribute__((ext_vector_type(16))) float f32x16;
typedef __attribute__((ext_vector_type(2))) unsigned int uint2v;
typedef __attribute__((ext_vector_type(4))) unsigned int uint4v;

#define DIM 1024
#define SLEN 2048
#define NH 16
#define HD 64

__device__ __forceinline__ f32x4 MFMA(bf16x8 a, bf16x8 b, f32x4 c) {
    return __builtin_amdgcn_mfma_f32_16x16x32_bf16(a, b, c, 0, 0, 0);
}
__device__ __forceinline__ f32x16 MFMA32(bf16x8 a, bf16x8 b, f32x16 c) {
    return __builtin_amdgcn_mfma_f32_32x32x16_bf16(a, b, c, 0, 0, 0);
}
__device__ __forceinline__ unsigned pack_bf16(float a, float b) {
    unsigned short ua = __builtin_bit_cast(unsigned short, (__bf16)a);
    unsigned short ub = __builtin_bit_cast(unsigned short, (__bf16)b);
    return ((unsigned)ub << 16) | (unsigned)ua;
}

// ---------------- f32 -> bf16 convert (n % 8 == 0) ----------------
__global__ __launch_bounds__(256) void cvt_bf16(const float* __restrict__ in,
                                                __bf16* __restrict__ out, int n) {
    int i = (blockIdx.x * blockDim.x + threadIdx.x) * 8;
    if (i >= n) return;
    f32x4 a = *reinterpret_cast<const f32x4*>(in + i);
    f32x4 b = *reinterpret_cast<const f32x4*>(in + i + 4);
    bf16x8 o;
#pragma unroll
    for (int j = 0; j < 4; ++j) { o[j] = (__bf16)a[j]; o[j + 4] = (__bf16)b[j]; }
    *reinterpret_cast<bf16x8*>(out + i) = o;
}

// 4 weight matrices in one launch (blockIdx.y selects)
__global__ __launch_bounds__(256) void cvt_w4(const float* __restrict__ w0,
                                              const float* __restrict__ w1,
                                              const float* __restrict__ w2,
                                              const float* __restrict__ w3,
                                              __bf16* __restrict__ o0,
                                              __bf16* __restrict__ o1,
                                              __bf16* __restrict__ o2,
                                              __bf16* __restrict__ o3) {
    int s = blockIdx.y;
    const float* in = s == 0 ? w0 : s == 1 ? w1 : s == 2 ? w2 : w3;
    __bf16* out = s == 0 ? o0 : s == 1 ? o1 : s == 2 ? o2 : o3;
    int i = (blockIdx.x * blockDim.x + threadIdx.x) * 8;
    f32x4 a = *reinterpret_cast<const f32x4*>(in + i);
    f32x4 b = *reinterpret_cast<const f32x4*>(in + i + 4);
    bf16x8 o;
#pragma unroll
    for (int j = 0; j < 4; ++j) { o[j] = (__bf16)a[j]; o[j + 4] = (__bf16)b[j]; }
    *reinterpret_cast<bf16x8*>(out + i) = o;
}

// ---------------- RoPE on q and k in one launch --------------------------------
__global__ __launch_bounds__(256) void rope2(__bf16* __restrict__ q,
                                             __bf16* __restrict__ k) {
    __bf16* t = blockIdx.y == 0 ? q : k;
    // fold softmax scale (1/8)*log2(e) into q so attention can use exp2
    const float scale = blockIdx.y == 0 ? 0.18033688011112042f : 1.0f;
    int idx = blockIdx.x * blockDim.x + threadIdx.x;
    int row = idx >> 9;
    int p = idx & 511;
    int head = p >> 5;
    int j = p & 31;
    int s = row & (SLEN - 1);
    float inv = expf(-0.28782313662425574f * (float)j);
    float angle = (float)s * inv;
    float sn, cs;
    sincosf(angle, &sn, &cs);
    size_t base = (size_t)row * DIM + head * HD + 2 * j;
    float e = (float)t[base], o = (float)t[base + 1];
    t[base] = (__bf16)((e * cs - o * sn) * scale);
    t[base + 1] = (__bf16)((e * sn + o * cs) * scale);
}

// ---------------- fused QKV GEMM: 128x128 tile, BK=64, swizzled LDS -----------
// Q,K row-major [token][dim]; V TRANSPOSED: Vt[(b*16+h)*64+d][s]
__global__ __launch_bounds__(256) void gemm_qkv(const __bf16* __restrict__ X,
                                                const __bf16* __restrict__ Wq,
                                                const __bf16* __restrict__ Wk,
                                                const __bf16* __restrict__ Wv,
                                                __bf16* __restrict__ Qo,
                                                __bf16* __restrict__ Ko,
                                                __bf16* __restrict__ Vt) {
    __shared__ alignas(16) __bf16 Alds[128 * 64];
    __shared__ alignas(16) __bf16 Blds[128 * 64];
    const int tid = threadIdx.x;
    const int lane = tid & 63;
    const int w = tid >> 6;
    const int wr = w >> 1, wc = w & 1;
    const int l15 = lane & 15, lhi = lane >> 4;
    const int l7 = l15 & 7;
    const int m0 = blockIdx.y * 128;
    const int n0g = blockIdx.x * 128;
    const int seg = n0g >> 10;
    const int n0 = n0g & 1023;
    const __bf16* __restrict__ B = seg == 0 ? Wq : seg == 1 ? Wk : Wv;
    const int K = 1024, N = 1024;

    const int lrow = lane >> 3;                 // 0..7
    const int scol = ((lane & 7) ^ lrow) * 8;   // source-side XOR swizzle

    f32x4 acc[4][4] = {};

    for (int kt = 0; kt < K; kt += 64) {
#pragma unroll
        for (int c = 0; c < 4; ++c) {
            int r0 = c * 32 + w * 8;
            const __bf16* sa = &X[(size_t)(m0 + r0 + lrow) * K + kt + scol];
            const __bf16* sb = &B[(size_t)(n0 + r0 + lrow) * K + kt + scol];
            __builtin_amdgcn_global_load_lds((const __attribute__((address_space(1))) void*)sa,
                                             (__attribute__((address_space(3))) void*)&Alds[r0 * 64],
                                             16, 0, 0);
            __builtin_amdgcn_global_load_lds((const __attribute__((address_space(1))) void*)sb,
                                             (__attribute__((address_space(3))) void*)&Blds[r0 * 64],
                                             16, 0, 0);
        }
        __syncthreads();
#pragma unroll
        for (int kk = 0; kk < 2; ++kk) {
            bf16x8 af[4], bfr[4];
#pragma unroll
            for (int i = 0; i < 4; ++i) {
                af[i] = *(const bf16x8*)&Alds[(wr * 64 + i * 16 + l15) * 64 + 8 * ((kk * 4 + lhi) ^ l7)];
                bfr[i] = *(const bf16x8*)&Blds[(wc * 64 + i * 16 + l15) * 64 + 8 * ((kk * 4 + lhi) ^ l7)];
            }
            __builtin_amdgcn_s_setprio(1);
#pragma unroll
            for (int i = 0; i < 4; ++i)
#pragma unroll
                for (int j = 0; j < 4; ++j)
                    acc[i][j] = MFMA(af[i], bfr[j], acc[i][j]);
            __builtin_amdgcn_s_setprio(0);
        }
        __syncthreads();
    }
    if (seg < 2) {
        __bf16* __restrict__ O = seg == 0 ? Qo : Ko;
#pragma unroll
        for (int i = 0; i < 4; ++i)
#pragma unroll
            for (int j = 0; j < 4; ++j)
#pragma unroll
                for (int r = 0; r < 4; ++r) {
                    int row = m0 + wr * 64 + i * 16 + lhi * 4 + r;
                    int col = n0 + wc * 64 + j * 16 + l15;
                    O[(size_t)row * N + col] = (__bf16)acc[i][j][r];
                }
    } else {
        // V: write transposed Vt[(b*16+h)*64 + d][s], packed over 4 consecutive s
#pragma unroll
        for (int i = 0; i < 4; ++i)
#pragma unroll
            for (int j = 0; j < 4; ++j) {
                int row = m0 + wr * 64 + i * 16 + lhi * 4;  // token base, mult of 4
                int col = n0 + wc * 64 + j * 16 + l15;      // dim
                int bb = row >> 11, s = row & 2047;
                int hh = col >> 6, d = col & 63;
                bf16x4 pk;
#pragma unroll
                for (int r = 0; r < 4; ++r) pk[r] = (__bf16)acc[i][j][r];
                *(bf16x4*)&Vt[((size_t)(bb * 16 + hh) * 64 + d) * SLEN + s] = pk;
            }
    }
}

// ---------------- O-projection GEMM: 64x128 tile, f32 out, 512 blocks ---------
__global__ __launch_bounds__(256) void gemm_o(const __bf16* __restrict__ A,
                                              const __bf16* __restrict__ B,
                                              float* __restrict__ C) {
    __shared__ alignas(16) __bf16 Alds[64 * 64];
    __shared__ alignas(16) __bf16 Blds[128 * 64];
    const int tid = threadIdx.x;
    const int lane = tid & 63;
    const int w = tid >> 6;
    const int wr = w >> 1, wc = w & 1;
    const int l15 = lane & 15, lhi = lane >> 4;
    const int l7 = l15 & 7;
    const int m0 = blockIdx.y * 64;
    const int n0 = blockIdx.x * 128;
    const int K = 1024, N = 1024;

    const int lrow = lane >> 3;
    const int scol = ((lane & 7) ^ lrow) * 8;

    f32x4 acc[2][4] = {};

    for (int kt = 0; kt < K; kt += 64) {
#pragma unroll
        for (int c = 0; c < 2; ++c) {
            int r0 = c * 32 + w * 8;
            const __bf16* sa = &A[(size_t)(m0 + r0 + lrow) * K + kt + scol];
            __builtin_amdgcn_global_load_lds((const __attribute__((address_space(1))) void*)sa,
                                             (__attribute__((address_space(3))) void*)&Alds[r0 * 64],
                                             16, 0, 0);
        }
#pragma unroll
        for (int c = 0; c < 4; ++c) {
            int r0 = c * 32 + w * 8;
            const __bf16* sb = &B[(size_t)(n0 + r0 + lrow) * K + kt + scol];
            __builtin_amdgcn_global_load_lds((const __attribute__((address_space(1))) void*)sb,
                                             (__attribute__((address_space(3))) void*)&Blds[r0 * 64],
                                             16, 0, 0);
        }
        __syncthreads();
#pragma unroll
        for (int kk = 0; kk < 2; ++kk) {
            bf16x8 af[2], bfr[4];
#pragma unroll
            for (int i = 0; i < 2; ++i)
                af[i] = *(const bf16x8*)&Alds[(wr * 32 + i * 16 + l15) * 64 + 8 * ((kk * 4 + lhi) ^ l7)];
#pragma unroll
            for (int j = 0; j < 4; ++j)
                bfr[j] = *(const bf16x8*)&Blds[(wc * 64 + j * 16 + l15) * 64 + 8 * ((kk * 4 + lhi) ^ l7)];
            __builtin_amdgcn_s_setprio(1);
#pragma unroll
            for (int i = 0; i < 2; ++i)
#pragma unroll
                for (int j = 0; j < 4; ++j)
                    acc[i][j] = MFMA(af[i], bfr[j], acc[i][j]);
            __builtin_amdgcn_s_setprio(0);
        }
        __syncthreads();
    }
#pragma unroll
    for (int i = 0; i < 2; ++i)
#pragma unroll
        for (int j = 0; j < 4; ++j)
#pragma unroll
            for (int r = 0; r < 4; ++r) {
                int row = m0 + wr * 32 + i * 16 + lhi * 4 + r;
                int col = n0 + wc * 64 + j * 16 + l15;
                C[(size_t)row * N + col] = acc[i][j][r];
            }
}

// ---------------- causal flash attention, 32x32 MFMA, P-in-register -----------
// 1024 blocks x 256 threads (4 waves = 2 q-halves x 2 key-halves), 64-q tile,
// proven LPT schedule. Lane owns q = lane&31 (C/D col). P^T B-fragments built
// from S registers via 2x permlane32_swap per 16-key slice (no P LDS traffic).
// Static softmax max (exp2(S-16)); row-sum by VALU adds; cross-(key-half) and
// cross-hi reduction in the epilogue reusing the K/V LDS. LDS = 32 KB -> 4/CU.
__global__ __launch_bounds__(256, 4) void attn_kernel(const __bf16* __restrict__ Q,
                                                      const __bf16* __restrict__ K,
                                                      const __bf16* __restrict__ Vt,
                                                      __bf16* __restrict__ Y) {
    __shared__ __bf16 Klds[2][64 * 64];   // [key][d-chunks swizzled]
    __shared__ __bf16 Vlds[2][64 * 64];   // [d][key-chunks swizzled]

    const int tid = threadIdx.x;
    const int lane = tid & 63;
    const int w = tid >> 6;               // 0..3
    const int qhalf = w & 1, khalf = w >> 1;
    const int l31 = lane & 31;
    const int hi32 = lane >> 5;
    const int l7 = l31 & 7;

    // id&7 = XCD; within XCD: qt descending (LPT), interleaved over 4 bh streams
    const int id = blockIdx.x;            // 0..1023
    const int x = id & 7, jj = id >> 3;   // jj 0..127
    const int qt = 31 - (jj >> 2);        // 31..0
    const int bh = 4 * x + (jj & 3);      // 4 streams per XCD (2MB L2 working set)
    const int b = bh >> 4, h = bh & 15;

    // staging (256 threads cover 64 rows x 128B, 2 iters, source-side swizzle)
    const int srow = lane >> 3;
    const int scs = (lane & 7) ^ srow;
    const __bf16* skP = K + (size_t)b * SLEN * DIM + h * HD + (size_t)(8 * w + srow) * DIM + scs * 8;
    const __bf16* svP = Vt + (size_t)bh * 64 * SLEN + (size_t)(8 * w + srow) * SLEN + scs * 8;
    const int dA = (8 * w + srow) * 64;

    auto stage = [&](int buf) {
#pragma unroll
        for (int i = 0; i < 2; ++i) {
            __builtin_amdgcn_global_load_lds(
                (const __attribute__((address_space(1))) void*)(skP + (size_t)i * 32 * DIM),
                (__attribute__((address_space(3))) void*)&Klds[buf][dA + i * 32 * 64], 16, 0, 0);
            __builtin_amdgcn_global_load_lds(
                (const __attribute__((address_space(1))) void*)(svP + (size_t)i * 32 * SLEN),
                (__attribute__((address_space(3))) void*)&Vlds[buf][dA + i * 32 * 64], 16, 0, 0);
        }
        skP += 64 * DIM;   // next kv tile: +64 key rows
        svP += 64;         // next kv tile: +64 key columns
    };

    // Q B-fragments (col q = l31, k = 16s + 8*hi32 + j), once from global
    const int qloc = qhalf * 32 + l31;
    const int qg = qt * 64 + qloc;
    const size_t qbase = (size_t)(b * SLEN + qg) * DIM + h * HD;
    bf16x8 qf0 = *(const bf16x8*)&Q[qbase + 0 + 8 * hi32];
    bf16x8 qf1 = *(const bf16x8*)&Q[qbase + 16 + 8 * hi32];
    bf16x8 qf2 = *(const bf16x8*)&Q[qbase + 32 + 8 * hi32];
    bf16x8 qf3 = *(const bf16x8*)&Q[qbase + 48 + 8 * hi32];

    // LDS fragment read offsets (chunk-swizzled, throughput-uniform)
    const int krowbase = (khalf * 32 + l31) * 64;
    const int koff0 = krowbase + 8 * ((0 + hi32) ^ l7);
    const int koff1 = krowbase + 8 * ((2 + hi32) ^ l7);
    const int koff2 = krowbase + 8 * ((4 + hi32) ^ l7);
    const int koff3 = krowbase + 8 * ((6 + hi32) ^ l7);
    const int vrow0 = l31 * 64, vrow1 = (32 + l31) * 64;
    const int voff00 = vrow0 + 8 * ((4 * khalf + 0 + hi32) ^ l7);   // db0, ss0
    const int voff01 = vrow0 + 8 * ((4 * khalf + 2 + hi32) ^ l7);   // db0, ss1
    const int voff10 = vrow1 + 8 * ((4 * khalf + 0 + hi32) ^ l7);   // db1, ss0
    const int voff11 = vrow1 + 8 * ((4 * khalf + 2 + hi32) ^ l7);   // db1, ss1

    f32x16 acc0 = {}, acc1 = {};  // O^T[d = (r&3)+8*(r>>2)+4*hi32 + 32*db][q=l31]
    float lsum = 0.f;

    const int nkt = qt + 1;  // kv tiles 0..qt
    stage(0);
    for (int kt = 0; kt < nkt; ++kt) {
        const int cur = kt & 1;
        __syncthreads();  // drains vmcnt: buf[cur] staged; buf[cur^1] free
        if (kt + 1 < nkt) stage(cur ^ 1);
        const __bf16* Kc = Klds[cur];
        const __bf16* Vc = Vlds[cur];

        // ---- S^T[32 keys][32 q] = K Q^T over 4 k-slices ----
        f32x16 S = {};
        __builtin_amdgcn_s_setprio(1);
        S = MFMA32(*(const bf16x8*)&Kc[koff0], qf0, S);
        S = MFMA32(*(const bf16x8*)&Kc[koff1], qf1, S);
        S = MFMA32(*(const bf16x8*)&Kc[koff2], qf2, S);
        S = MFMA32(*(const bf16x8*)&Kc[koff3], qf3, S);
        __builtin_amdgcn_s_setprio(0);

        if (kt == qt) {  // only the diagonal tile is partially masked
#pragma unroll
            for (int r = 0; r < 16; ++r) {
                const int krow = (r & 3) + 8 * (r >> 2) + 4 * hi32 + 32 * khalf;
                if (krow > qloc) S[r] = -1e30f;
            }
        }
        // ---- P = exp2(S - 16) (static max); partial row-sum (own 16 keys) ----
        float p[16];
#pragma unroll
        for (int r = 0; r < 16; ++r) p[r] = exp2f(S[r] - 16.0f);
        float s0 = (p[0] + p[1]) + (p[2] + p[3]);
        float s1 = (p[4] + p[5]) + (p[6] + p[7]);
        float s2 = (p[8] + p[9]) + (p[10] + p[11]);
        float s3 = (p[12] + p[13]) + (p[14] + p[15]);
        lsum += (s0 + s1) + (s2 + s3);

        // ---- build P^T B-fragments in-register via permlane32_swap ----
        bf16x8 pf[2];
#pragma unroll
        for (int ss = 0; ss < 2; ++ss) {
            unsigned P01 = pack_bf16(p[8 * ss + 0], p[8 * ss + 1]);
            unsigned P23 = pack_bf16(p[8 * ss + 2], p[8 * ss + 3]);
            unsigned Q01 = pack_bf16(p[8 * ss + 4], p[8 * ss + 5]);
            unsigned Q23 = pack_bf16(p[8 * ss + 6], p[8 * ss + 7]);
            uint2v sa = __builtin_amdgcn_permlane32_swap(P01, Q01, false, false);
            uint2v sb = __builtin_amdgcn_permlane32_swap(P23, Q23, false, false);
            uint4v pwv = {sa[0], sb[0], sa[1], sb[1]};
            pf[ss] = __builtin_bit_cast(bf16x8, pwv);
        }

        // ---- O^T += V^T P^T ----
        __builtin_amdgcn_s_setprio(1);
        acc0 = MFMA32(*(const bf16x8*)&Vc[voff00], pf[0], acc0);
        acc0 = MFMA32(*(const bf16x8*)&Vc[voff01], pf[1], acc0);
        acc1 = MFMA32(*(const bf16x8*)&Vc[voff10], pf[0], acc1);
        acc1 = MFMA32(*(const bf16x8*)&Vc[voff11], pf[1], acc1);
        __builtin_amdgcn_s_setprio(0);
    }

    // ---- epilogue: reduce across key-halves (LDS, reusing K/V buffers),
    //      then across hi32 for lsum; divide; store ----
    float* fbuf = (float*)&Klds[0][0];       // 4096 f32 = 16 KB (exactly Klds)
    float* lbuf = (float*)&Vlds[0][0];       // lsum exchange
    __syncthreads();                         // all compute on Klds/Vlds done
    if (khalf == 1) {
#pragma unroll
        for (int r = 0; r < 16; ++r) {
            fbuf[(qhalf * 2 + 0) * 1024 + r * 64 + lane] = acc0[r];
            fbuf[(qhalf * 2 + 1) * 1024 + r * 64 + lane] = acc1[r];
        }
        lbuf[qhalf * 64 + lane] = lsum;
    }
    __syncthreads();
    if (khalf == 0) {
#pragma unroll
        for (int r = 0; r < 16; ++r) {
            acc0[r] += fbuf[(qhalf * 2 + 0) * 1024 + r * 64 + lane];
            acc1[r] += fbuf[(qhalf * 2 + 1) * 1024 + r * 64 + lane];
        }
        lsum += lbuf[qhalf * 64 + lane];
        lsum += __shfl_xor(lsum, 32);        // combine hi32 halves (same q)
        const float inv = 1.0f / lsum;
        const size_t obase = (size_t)(b * SLEN + qg) * DIM + h * HD;
#pragma unroll
        for (int g = 0; g < 4; ++g) {
            bf16x4 o0, o1;
#pragma unroll
            for (int e = 0; e < 4; ++e) {
                o0[e] = (__bf16)(acc0[g * 4 + e] * inv);
                o1[e] = (__bf16)(acc1[g * 4 + e] * inv);
            }
            *(bf16x4*)&Y[obase + 8 * g + 4 * hi32] = o0;
            *(bf16x4*)&Y[obase + 32 + 8 * g + 4 * hi32] = o1;
        }
    }
}

// ---------------- launcher ----------------
extern "C" void kernel_launch(void* const* d_in, const int* in_sizes, int n_in,
                              void* d_out, int out_size, void* d_ws, size_t ws_size,
                              hipStream_t stream) {
    const float* x = (const float*)d_in[0];
    const float* Wq = (const float*)d_in[1];
    const float* Wk = (const float*)d_in[2];
    const float* Wv = (const float*)d_in[3];
    const float* Wo = (const float*)d_in[4];
    float* out = (float*)d_out;

    const size_t XN = (size_t)4096 * 1024;
    const size_t WN = (size_t)1024 * 1024;

    __bf16* xb = (__bf16*)d_ws;
    __bf16* qb = xb + XN;
    __bf16* kb = qb + XN;
    __bf16* vtb = kb + XN;   // transposed V: [(b*16+h)*64 + d][SLEN]
    __bf16* wqb = vtb + XN;
    __bf16* wkb = wqb + WN;
    __bf16* wvb = wkb + WN;
    __bf16* wob = wvb + WN;
    __bf16* yb = xb;  // alias: attn writes y after x's last read (QKV GEMM)

    cvt_bf16<<<XN / 8 / 256, 256, 0, stream>>>(x, xb, (int)XN);
    dim3 gw(WN / 8 / 256, 4);
    cvt_w4<<<gw, 256, 0, stream>>>(Wq, Wk, Wv, Wo, wqb, wkb, wvb, wob);

    dim3 gq(24, 32);  // 3072/128 x 4096/128
    gemm_qkv<<<gq, 256, 0, stream>>>(xb, wqb, wkb, wvb, qb, kb, vtb);

    int pairs = 4096 * (DIM / 2);
    dim3 gr(pairs / 256, 2);
    rope2<<<gr, 256, 0, stream>>>(qb, kb);

    attn_kernel<<<1024, 256, 0, stream>>>(qb, kb, vtb, yb);

    dim3 go(8, 64);  // 1024/128 x 4096/64
    gemm_o<<<go, 256, 0, stream>>>(yb, wob, out);
}